// Round 2
// baseline (386.133 us; speedup 1.0000x reference)
//
#include <hip/hip_runtime.h>
#include <hip/hip_bf16.h>
#include <stdint.h>

#define B_   256
#define C_   10
#define S_   500
#define H_   256
#define OUT_ 500
#define M_   (B_ * S_)   // 128000 LSTM rows
#define FCK  (S_ * H_)   // 128000 fc inner dim

typedef __attribute__((ext_vector_type(8))) short s16x8;   // 8 bf16
typedef __attribute__((ext_vector_type(4))) float f32x4;

__device__ __forceinline__ unsigned short f2bf(float f) {
  union { float f; unsigned u; } v; v.f = f;
  unsigned r = v.u + 0x7fffu + ((v.u >> 16) & 1u);   // RNE
  return (unsigned short)(r >> 16);
}
__device__ __forceinline__ float sigf(float x) { return 1.0f / (1.0f + __expf(-x)); }
__device__ __forceinline__ float tanh_f(float x) { return 1.0f - 2.0f / (__expf(2.0f * x) + 1.0f); }

__device__ __forceinline__ void gload16(const void* g, void* l) {
  __builtin_amdgcn_global_load_lds((const __attribute__((address_space(1))) void*)g,
                                   (__attribute__((address_space(3))) void*)l, 16, 0, 0);
}

// ---- conv center tap + relu: y[b*S+s] = relu(sum_c x[b,c,s]*cw[c,2] + cb) ----
__global__ void k_conv(const float* __restrict__ x, const float* __restrict__ cw,
                       const float* __restrict__ cb, float* __restrict__ y) {
  int n = blockIdx.x * 256 + threadIdx.x;            // 128000 exact
  int b = n / S_, s = n - b * S_;
  const float* xp = x + (size_t)b * C_ * S_ + s;
  float acc = cb[0];
#pragma unroll
  for (int c = 0; c < C_; ++c) acc += xp[c * S_] * cw[c * 5 + 2];
  y[n] = fmaxf(acc, 0.0f);
}

// ---- w_ih1 fp32 -> bf16 ----
__global__ void k_cvtw1(const float* __restrict__ w, unsigned short* __restrict__ wb) {
  int i = blockIdx.x * 256 + threadIdx.x;            // 262144 exact
  wb[i] = f2bf(w[i]);
}

// ---- LSTM0 (scalar input, zero state, f-gate dead): h0[n][k] bf16 ----
__global__ void k_h0(const float* __restrict__ y, const float* __restrict__ w0,
                     const float* __restrict__ bi0, const float* __restrict__ bh0,
                     unsigned short* __restrict__ h0) {
  int gid = blockIdx.x * 256 + threadIdx.x;          // 8,192,000 exact
  int n = gid >> 6, q = gid & 63;
  int k = q * 4;
  float yv = y[n];
  f32x4 wi = *(const f32x4*)&w0[k];
  f32x4 wg = *(const f32x4*)&w0[512 + k];
  f32x4 wo = *(const f32x4*)&w0[768 + k];
  f32x4 bii = *(const f32x4*)&bi0[k];
  f32x4 big = *(const f32x4*)&bi0[512 + k];
  f32x4 bio = *(const f32x4*)&bi0[768 + k];
  f32x4 bhi = *(const f32x4*)&bh0[k];
  f32x4 bhg = *(const f32x4*)&bh0[512 + k];
  f32x4 bho = *(const f32x4*)&bh0[768 + k];
  ushort4 o;
  unsigned short* op = (unsigned short*)&o;
#pragma unroll
  for (int j = 0; j < 4; ++j) {
    float gi = yv * wi[j] + bii[j] + bhi[j];
    float gg = yv * wg[j] + big[j] + bhg[j];
    float go = yv * wo[j] + bio[j] + bho[j];
    float c = sigf(gi) * tanh_f(gg);
    op[j] = f2bf(sigf(go) * tanh_f(c));
  }
  *(ushort4*)&h0[(size_t)n * 256 + k] = o;
}

// ---- GEMM1: gates = h0 @ Wb^T (3 gate strips), fused activation -> h1 bf16 ----
// tile: BM=128 rows x 64 k-cols x 3 gates, BK=64, K=256
__global__ __launch_bounds__(256) void k_gemm1(
    const unsigned short* __restrict__ A,    // h0 [M][256] bf16
    const unsigned short* __restrict__ Wb,   // [1024][256] bf16
    const float* __restrict__ b1i, const float* __restrict__ b1h,
    unsigned short* __restrict__ h1) {
  __shared__ __align__(16) unsigned short As[128 * 64];  // 16 KB
  __shared__ __align__(16) unsigned short Bs[192 * 64];  // 24 KB
  const int t = threadIdx.x, lane = t & 63, w = t >> 6;
  const int m0 = blockIdx.x * 128;
  const int kc0 = blockIdx.y * 64;
  f32x4 acc[2][3][4] = {};

  for (int kt = 0; kt < 4; ++kt) {
    // stage A: 1024 chunks of 16B (128 rows x 8 chunks)
#pragma unroll
    for (int it = 0; it < 4; ++it) {
      int chunk = it * 256 + w * 64 + lane;
      int r = chunk >> 3, c = (chunk & 7) * 8;
      gload16(A + (size_t)(m0 + r) * 256 + kt * 64 + c,
              (void*)&As[(it * 256 + w * 64) * 8]);
    }
    // stage B: 1536 chunks (192 rows x 8 chunks); gate g=r>>6 (i,g,o -> 0/512/768)
#pragma unroll
    for (int it = 0; it < 6; ++it) {
      int chunk = it * 256 + w * 64 + lane;
      int r = chunk >> 3, c = (chunk & 7) * 8;
      int g = r >> 6, kl = r & 63;
      int gbase = (g == 0) ? 0 : (g == 1 ? 512 : 768);
      gload16(Wb + (size_t)(gbase + kc0 + kl) * 256 + kt * 64 + c,
              (void*)&Bs[(it * 256 + w * 64) * 8]);
    }
    __syncthreads();
#pragma unroll
    for (int kk = 0; kk < 2; ++kk) {
      int ko = kk * 32 + (lane >> 4) * 8;
      s16x8 a0 = *(const s16x8*)&As[(w * 32 + (lane & 15)) * 64 + ko];
      s16x8 a1 = *(const s16x8*)&As[(w * 32 + 16 + (lane & 15)) * 64 + ko];
#pragma unroll
      for (int g = 0; g < 3; ++g) {
#pragma unroll
        for (int n = 0; n < 4; ++n) {
          s16x8 b = *(const s16x8*)&Bs[(g * 64 + n * 16 + (lane & 15)) * 64 + ko];
          acc[0][g][n] = __builtin_amdgcn_mfma_f32_16x16x32_bf16(a0, b, acc[0][g][n], 0, 0, 0);
          acc[1][g][n] = __builtin_amdgcn_mfma_f32_16x16x32_bf16(a1, b, acc[1][g][n], 0, 0, 0);
        }
      }
    }
    __syncthreads();
  }
  // epilogue: h = sig(go)*tanh(sig(gi)*tanh(gg))
#pragma unroll
  for (int n = 0; n < 4; ++n) {
    int kglob = kc0 + n * 16 + (lane & 15);
    float bi = b1i[kglob] + b1h[kglob];
    float bg = b1i[512 + kglob] + b1h[512 + kglob];
    float bo = b1i[768 + kglob] + b1h[768 + kglob];
#pragma unroll
    for (int m = 0; m < 2; ++m) {
#pragma unroll
      for (int r = 0; r < 4; ++r) {
        int row = m0 + w * 32 + m * 16 + (lane >> 4) * 4 + r;
        float gi = acc[m][0][n][r] + bi;
        float gg = acc[m][1][n][r] + bg;
        float go = acc[m][2][n][r] + bo;
        float c = sigf(gi) * tanh_f(gg);
        h1[(size_t)row * 256 + kglob] = f2bf(sigf(go) * tanh_f(c));
      }
    }
  }
}

// ---- out init: out[b][o] = fc_b[o] ----
__global__ void k_initout(const float* __restrict__ fcb, float* __restrict__ out) {
  int i = blockIdx.x * 256 + threadIdx.x;            // 128000 exact
  out[i] = fcb[i % OUT_];
}

// ---- GEMM2: out += feat(=h1 flat [256][128000]) @ fc_w^T ; split-K, atomics ----
// tile: BM=256 (all), BN=128 (grid.x=4, pad 512), Kchunk=1024 (grid.y=125), BK=64
__global__ __launch_bounds__(512) void k_gemm2(
    const unsigned short* __restrict__ A,    // h1 viewed [256][128000] bf16
    const float* __restrict__ W,             // fc_w [500][128000] f32
    float* __restrict__ out) {
  __shared__ __align__(16) unsigned short As[256 * 64];  // 32 KB
  __shared__ __align__(16) float Ws[128 * 64];           // 32 KB
  const int t = threadIdx.x, lane = t & 63, w = t >> 6;
  const int n0 = blockIdx.x * 128;
  const size_t kbase = (size_t)blockIdx.y * 1024;
  const int wm = w >> 1, wn = w & 1;
  f32x4 acc[4][4] = {};

  for (int kt = 0; kt < 16; ++kt) {
    size_t kofs = kbase + (size_t)kt * 64;
    // A: 2048 chunks of 16B (256 rows x 8 chunks)
#pragma unroll
    for (int it = 0; it < 4; ++it) {
      int chunk = it * 512 + w * 64 + lane;
      int r = chunk >> 3, c = (chunk & 7) * 8;
      gload16(A + (size_t)r * FCK + kofs + c, (void*)&As[(it * 512 + w * 64) * 8]);
    }
    // W: 128 rows x 64 f32 (16 chunks/row), clamp padded rows
#pragma unroll
    for (int it = 0; it < 4; ++it) {
      int chunk = it * 512 + w * 64 + lane;
      int r = chunk >> 4, c = (chunk & 15) * 4;
      int nrow = n0 + r; if (nrow > 499) nrow = 499;
      gload16(W + (size_t)nrow * FCK + kofs + c, (void*)&Ws[(it * 512 + w * 64) * 4]);
    }
    __syncthreads();
#pragma unroll
    for (int kk = 0; kk < 2; ++kk) {
      int ko = kk * 32 + (lane >> 4) * 8;
      s16x8 af[4];
#pragma unroll
      for (int m = 0; m < 4; ++m)
        af[m] = *(const s16x8*)&As[(wm * 64 + m * 16 + (lane & 15)) * 64 + ko];
#pragma unroll
      for (int n = 0; n < 4; ++n) {
        int brow = wn * 64 + n * 16 + (lane & 15);
        f32x4 w0 = *(const f32x4*)&Ws[brow * 64 + ko];
        f32x4 w1 = *(const f32x4*)&Ws[brow * 64 + ko + 4];
        s16x8 b;
#pragma unroll
        for (int j = 0; j < 4; ++j) {
          b[j] = (short)f2bf(w0[j]);
          b[4 + j] = (short)f2bf(w1[j]);
        }
#pragma unroll
        for (int m = 0; m < 4; ++m)
          acc[m][n] = __builtin_amdgcn_mfma_f32_16x16x32_bf16(af[m], b, acc[m][n], 0, 0, 0);
      }
    }
    __syncthreads();
  }
#pragma unroll
  for (int m = 0; m < 4; ++m) {
#pragma unroll
    for (int n = 0; n < 4; ++n) {
      int col = n0 + wn * 64 + n * 16 + (lane & 15);
      if (col < OUT_) {
#pragma unroll
        for (int r = 0; r < 4; ++r) {
          int row = wm * 64 + m * 16 + (lane >> 4) * 4 + r;
          atomicAdd(&out[(size_t)row * OUT_ + col], acc[m][n][r]);
        }
      }
    }
  }
}

extern "C" void kernel_launch(void* const* d_in, const int* in_sizes, int n_in,
                              void* d_out, int out_size, void* d_ws, size_t ws_size,
                              hipStream_t stream) {
  const float* x      = (const float*)d_in[0];
  const float* conv_w = (const float*)d_in[1];
  const float* conv_b = (const float*)d_in[2];
  const float* w_ih0  = (const float*)d_in[3];
  const float* b_ih0  = (const float*)d_in[4];
  const float* b_hh0  = (const float*)d_in[5];
  const float* w_ih1  = (const float*)d_in[6];
  const float* b_ih1  = (const float*)d_in[7];
  const float* b_hh1  = (const float*)d_in[8];
  const float* fc_w   = (const float*)d_in[9];
  const float* fc_b   = (const float*)d_in[10];
  float* out = (float*)d_out;

  char* ws = (char*)d_ws;
  float* y           = (float*)ws;                               // 512000 B
  unsigned short* w1b = (unsigned short*)(ws + 512000);          // 524288 B
  unsigned short* h0  = (unsigned short*)(ws + 1048576);         // 65,536,000 B
  unsigned short* h1  = (unsigned short*)(ws + 1048576 + 65536000ull);

  k_conv<<<500, 256, 0, stream>>>(x, conv_w, conv_b, y);
  k_cvtw1<<<1024, 256, 0, stream>>>(w_ih1, w1b);
  k_h0<<<32000, 256, 0, stream>>>(y, w_ih0, b_ih0, b_hh0, h0);
  k_gemm1<<<dim3(1000, 4), 256, 0, stream>>>(h0, w1b, b_ih1, b_hh1, h1);
  k_initout<<<500, 256, 0, stream>>>(fc_b, out);
  k_gemm2<<<dim3(4, 125), 512, 0, stream>>>(h1, fc_w, out);
}